// Round 8
// baseline (2863.562 us; speedup 1.0000x reference)
//
#include <hip/hip_runtime.h>
#include <hip/hip_fp16.h>

typedef _Float16 f16;
typedef __attribute__((ext_vector_type(8))) _Float16 f16x8;
typedef __attribute__((ext_vector_type(4))) _Float16 f16x4;
typedef __attribute__((ext_vector_type(4))) float f32x4;
typedef __attribute__((ext_vector_type(4))) float float4v;
typedef __attribute__((ext_vector_type(4))) unsigned int u32x4;

// Shapes: x[512,256,256], carry0[256,256], Wi[256,768], bi[768],
//         Wh[256,768], bhn[256], Wo[256,16], bo[16] -> out[512,256,16] f32
//
// gx workspace layout (scan-fragment order, produced by K1), f16:
//   vecidx = ((t*16 + blk)*8 + w8)*6 + (gate*2 + nt2)   [w8: 32-col groups]
//   element = vecidx*256 + lane*4 + j

#define BARLITE() asm volatile("s_waitcnt lgkmcnt(0)\n\ts_barrier" ::: "memory")

static __device__ __forceinline__ float sigm(float x) {
  return __builtin_amdgcn_rcpf(1.0f + __expf(-x));
}
static __device__ __forceinline__ float tanh_fast(float x) {
  float e = __expf(2.0f * x);
  return 1.0f - 2.0f * __builtin_amdgcn_rcpf(e + 1.0f);
}

// ---------------- K0: transpose+convert Wi -> WiT[768][256] f16 -------------
__global__ void k_prep_wit(const float* __restrict__ Wi, f16* __restrict__ WiT) {
  int n = blockIdx.x;
  int k = threadIdx.x;
  WiT[n * 256 + k] = (f16)Wi[(size_t)k * 768 + n];
}

// ---------------- K1: gx = x @ Wi + bi  (fp16 MFMA, 128x128 tile) -----------
__global__ __launch_bounds__(256, 4) void k_gemm_gx(
    const float* __restrict__ x, const f16* __restrict__ WiT,
    const float* __restrict__ bi, f16* __restrict__ gx) {
  __shared__ f16 As[128 * 64];
  __shared__ f16 Bs[128 * 64];
  const int tid = threadIdx.x;
  const int lane = tid & 63;
  const int wave = tid >> 6;
  const int wm = wave >> 1, wn = wave & 1;
  const int m0 = blockIdx.y * 128;
  const int n0 = blockIdx.x * 128;

  f32x4 acc[4][4] = {};

  for (int ks = 0; ks < 4; ++ks) {
    const int k0 = ks * 64;
#pragma unroll
    for (int i = 0; i < 8; ++i) {
      int c = i * 256 + tid;
      int row = c >> 4, cx = c & 15;
      float4v v = *reinterpret_cast<const float4v*>(
          x + (size_t)(m0 + row) * 256 + k0 + cx * 4);
      f16x4 hv;
      hv[0] = (f16)v[0]; hv[1] = (f16)v[1]; hv[2] = (f16)v[2]; hv[3] = (f16)v[3];
      int boff = row * 128 + ((cx * 8) ^ ((row & 7) << 4));
      *reinterpret_cast<f16x4*>(reinterpret_cast<char*>(As) + boff) = hv;
    }
#pragma unroll
    for (int i = 0; i < 4; ++i) {
      int c = i * 256 + tid;
      int n = c >> 3, cx = c & 7;
      f16x8 v = *reinterpret_cast<const f16x8*>(
          WiT + (size_t)(n0 + n) * 256 + k0 + cx * 8);
      int boff = n * 128 + ((cx * 16) ^ ((n & 7) << 4));
      *reinterpret_cast<f16x8*>(reinterpret_cast<char*>(Bs) + boff) = v;
    }
    __syncthreads();
#pragma unroll
    for (int kt = 0; kt < 2; ++kt) {
      const int kb = kt * 64 + ((lane >> 4) << 4);
      f16x8 a[4], b[4];
#pragma unroll
      for (int mt = 0; mt < 4; ++mt) {
        int r = wm * 64 + mt * 16 + (lane & 15);
        a[mt] = *reinterpret_cast<const f16x8*>(
            reinterpret_cast<const char*>(As) + r * 128 + (kb ^ ((r & 7) << 4)));
      }
#pragma unroll
      for (int nt = 0; nt < 4; ++nt) {
        int r = wn * 64 + nt * 16 + (lane & 15);
        b[nt] = *reinterpret_cast<const f16x8*>(
            reinterpret_cast<const char*>(Bs) + r * 128 + (kb ^ ((r & 7) << 4)));
      }
#pragma unroll
      for (int mt = 0; mt < 4; ++mt)
#pragma unroll
        for (int nt = 0; nt < 4; ++nt)
          acc[mt][nt] = __builtin_amdgcn_mfma_f32_16x16x32_f16(
              a[mt], b[nt], acc[mt][nt], 0, 0, 0);
    }
    __syncthreads();
  }
  const int t_  = blockIdx.y >> 1;
  const int bhf = blockIdx.y & 1;
  const int gg  = blockIdx.x >> 1;
  const int xh  = blockIdx.x & 1;
  float biv[4];
#pragma unroll
  for (int nt = 0; nt < 4; ++nt) biv[nt] = bi[n0 + wn * 64 + nt * 16 + (lane & 15)];
#pragma unroll
  for (int mt = 0; mt < 4; ++mt) {
    const int blk = bhf * 8 + wm * 4 + mt;
#pragma unroll
    for (int nt = 0; nt < 4; ++nt) {
      const int w = xh * 4 + wn * 2 + (nt >> 1);
      const int vecidx = ((t_ * 16 + blk) * 8 + w) * 6 + gg * 2 + (nt & 1);
      f16x4 hv;
#pragma unroll
      for (int r = 0; r < 4; ++r) hv[r] = (f16)(acc[mt][nt][r] + biv[nt]);
      *reinterpret_cast<f16x4*>(gx + (size_t)vecidx * 256 + lane * 4) = hv;
    }
  }
}

// ---------------- K2: pairwise col-split GRU scan, 32 blocks x 8 waves ------
// Block (pr = blk&15, hf = blk>>4): batch rows 16pr..+15, h-cols hf*128..+127.
// All Wh weights for the block's cols live in VGPRs (96/wave). Full h kept as
// MFMA A-frags in an 8-slot LDS ring; own half written locally each step,
// partner half exchanged through L2 with per-wave flag bits (release/acquire).
// Step: P1 own-kt MFMAs -> P2 import partner h_t (waves 4-7) | barrier ->
// P3 partner-kt MFMAs (+batched head every 8 steps) -> P4 elementwise +
// own A-frag write | barrier -> P5 export h_{t+1} + flag (waves 0-3).
__global__ __launch_bounds__(512, 2) void k_scan(
    const float* __restrict__ carry0, const float* __restrict__ Wh,
    const float* __restrict__ bhn, const f16* __restrict__ gxL,
    const float* __restrict__ Wo, const float* __restrict__ bo,
    float* __restrict__ out, char* __restrict__ xchg,
    unsigned int* __restrict__ flags) {
  __shared__ f16 ha[8 * 4096];  // 64 KB: h ring, 8 slots x (8 frames x 1KB)
  __shared__ f16 wofs[4096];    // 8 KB: Wo B-frags
  const int tid = threadIdx.x;
  const int lane = tid & 63;
  const int wave = tid >> 6;  // 0..7
  const int l15 = lane & 15, l4 = lane >> 4;
  const int pr = blockIdx.x & 15;
  const int hf = blockIdx.x >> 4;
  const int hf4 = hf * 4, pf4 = 4 - hf4;
  const int r0 = pr * 16;
  const int mycol = hf * 128 + wave * 16 + l15;  // own h-col (per l15)

  const int own = pr * 2 + hf, partner = pr * 2 + (1 - hf);
  char* xchgWr = xchg + (size_t)own * 8192;
  const char* xchgRd = xchg + (size_t)partner * 8192;
  unsigned int* flagOwn = flags + own * 520;
  const unsigned int* flagPartner = flags + partner * 520;

  // Wh all 3 gates for own cols -> 96 regs. whf*[i] holds kt=(hf4+i)&7 so
  // i=0..3 are own-half K-rows, i=4..7 partner-half (static reg indexing).
  f16x8 whf0[8], whf1[8], whf2[8];
#pragma unroll
  for (int i = 0; i < 8; ++i) {
    const int ktp = (hf4 + i) & 7;
#pragma unroll
    for (int e = 0; e < 8; ++e) {
      const size_t kr = (size_t)(ktp * 32 + l4 * 8 + e) * 768;
      whf0[i][e] = (f16)Wh[kr + mycol];
      whf1[i][e] = (f16)Wh[kr + 256 + mycol];
      whf2[i][e] = (f16)Wh[kr + 512 + mycol];
    }
  }
  // Wo -> LDS B-frags; wave w builds frame kt=w
  {
    f16x8 v;
#pragma unroll
    for (int e = 0; e < 8; ++e)
      v[e] = (f16)Wo[(wave * 32 + l4 * 8 + e) * 16 + l15];
    *reinterpret_cast<f16x8*>(reinterpret_cast<char*>(wofs) + wave * 1024 +
                              lane * 16) = v;
  }
  const float bh = bhn[mycol];
  const float bov = bo[l15];

  // init: full h_0 A-frags into ring slot 0 (both halves), hcur = own cols
  float hcur[4];
#pragma unroll
  for (int nt2 = 0; nt2 < 2; ++nt2) {
    const int c = wave * 32 + nt2 * 16 + l15;
    const int f = c >> 5;
    const int s = (c >> 3) & 3;
#pragma unroll
    for (int j = 0; j < 4; ++j) {
      const int row = l4 * 4 + j;
      const int gl = s * 16 + row;
      const int p = gl ^ (gl >> 3);
      *reinterpret_cast<f16*>(reinterpret_cast<char*>(ha) + f * 1024 + p * 16 +
                              (c & 7) * 2) = (f16)carry0[(size_t)(r0 + row) * 256 + c];
    }
  }
#pragma unroll
  for (int j = 0; j < 4; ++j)
    hcur[j] = carry0[(size_t)(r0 + l4 * 4 + j) * 256 + mycol];
  __syncthreads();

  const int rdoff = (lane ^ (lane >> 3)) * 16;
  // gx: this thread's 3 gate values live at gpt + g*512 (f16 elems), stride/t 196608
  const f16* gpt = gxL + ((size_t)pr * 8 + hf4 + (wave >> 1)) * 1536 +
                   (size_t)(wave & 1) * 256 + (size_t)lane * 4;
  f16x4 gv0 = *reinterpret_cast<const f16x4*>(gpt);
  f16x4 gv1 = *reinterpret_cast<const f16x4*>(gpt + 512);
  f16x4 gv2 = *reinterpret_cast<const f16x4*>(gpt + 1024);

  // A-frag write constants for own cols
  const int fme = hf4 + (wave >> 1);
  const int sme = (wave & 1) * 2 + (l15 >> 3);
  const int cby = (l15 & 7) * 2;

  auto head_tau = [&](int tau) {
    const int sbase = (tau & 7) * 8192;
    f32x4 aco = {};
#pragma unroll
    for (int kt = 0; kt < 8; ++kt) {
      f16x8 a = *reinterpret_cast<const f16x8*>(
          reinterpret_cast<const char*>(ha) + sbase + kt * 1024 + rdoff);
      f16x8 wb = *reinterpret_cast<const f16x8*>(
          reinterpret_cast<const char*>(wofs) + kt * 1024 + lane * 16);
      aco = __builtin_amdgcn_mfma_f32_16x16x32_f16(a, wb, aco, 0, 0, 0);
    }
#pragma unroll
    for (int r = 0; r < 4; ++r) {
      float y = aco[r] + bov;
      if (l15 >= 8) y = __expf(fminf(fmaxf(y, -20.0f), 2.0f));
      out[((size_t)(tau - 1) * 256 + r0 + l4 * 4 + r) * 16 + l15] = y;
    }
  };

  for (int t = 0; t < 512; ++t) {
    const int cur = (t & 7) * 8192;
    const int nxt = ((t + 1) & 7) * 8192;
    const f16* gnx = gpt + (size_t)(t + 1 < 512 ? t + 1 : 511) * 196608;
    f16x4 gn0 = *reinterpret_cast<const f16x4*>(gnx);
    f16x4 gn1 = *reinterpret_cast<const f16x4*>(gnx + 512);
    f16x4 gn2 = *reinterpret_cast<const f16x4*>(gnx + 1024);

    // ---- P1: own-half K MFMAs (frames hf4..hf4+3, written locally) ----
    f32x4 acc0 = {}, acc1 = {}, acc2 = {};
#pragma unroll
    for (int i = 0; i < 4; ++i) {
      f16x8 a = *reinterpret_cast<const f16x8*>(
          reinterpret_cast<const char*>(ha) + cur + (hf4 + i) * 1024 + rdoff);
      acc0 = __builtin_amdgcn_mfma_f32_16x16x32_f16(a, whf0[i], acc0, 0, 0, 0);
      acc1 = __builtin_amdgcn_mfma_f32_16x16x32_f16(a, whf1[i], acc1, 0, 0, 0);
      acc2 = __builtin_amdgcn_mfma_f32_16x16x32_f16(a, whf2[i], acc2, 0, 0, 0);
    }

    // ---- P2: waves 4-7 import partner half of h_t into slot cur ----
    if (wave >= 4 && t > 0) {
      const unsigned msk = 1u << (wave - 4);
      while (!(__hip_atomic_load(flagPartner + t, __ATOMIC_ACQUIRE,
                                 __HIP_MEMORY_SCOPE_AGENT) & msk)) {}
      u32x4 d = *reinterpret_cast<const u32x4*>(
          xchgRd + (size_t)(t & 1) * 4096 + (wave - 4) * 1024 + lane * 16);
      *reinterpret_cast<u32x4*>(reinterpret_cast<char*>(ha) + cur +
                                (pf4 + (wave - 4)) * 1024 + lane * 16) = d;
    }
    BARLITE();

    // ---- P3: partner-half K MFMAs (frames pf4..pf4+3) ----
#pragma unroll
    for (int i = 0; i < 4; ++i) {
      f16x8 a = *reinterpret_cast<const f16x8*>(
          reinterpret_cast<const char*>(ha) + cur + (pf4 + i) * 1024 + rdoff);
      acc0 = __builtin_amdgcn_mfma_f32_16x16x32_f16(a, whf0[4 + i], acc0, 0, 0, 0);
      acc1 = __builtin_amdgcn_mfma_f32_16x16x32_f16(a, whf1[4 + i], acc1, 0, 0, 0);
      acc2 = __builtin_amdgcn_mfma_f32_16x16x32_f16(a, whf2[4 + i], acc2, 0, 0, 0);
    }
    // batched heads every 8 steps (hf0: taus t-7..t-4, hf1: t-3..t); the
    // extra barrier keeps P4's ring overwrite off the head's slots
    if ((t & 7) == 0 && t > 0) {
      if (wave < 4) head_tau(t - 7 + hf4 + wave);
      BARLITE();
    }

    // ---- P4: elementwise GRU + own A-frag write into slot nxt ----
#pragma unroll
    for (int j = 0; j < 4; ++j) {
      float rg = sigm((float)gv0[j] + acc0[j]);
      float zg = sigm((float)gv1[j] + acc1[j]);
      float ng = tanh_fast((float)gv2[j] + rg * (acc2[j] + bh));
      float h = ng + zg * (hcur[j] - ng);
      hcur[j] = h;
      const int gl = sme * 16 + l4 * 4 + j;
      const int p = gl ^ (gl >> 3);
      *reinterpret_cast<f16*>(reinterpret_cast<char*>(ha) + nxt + fme * 1024 +
                              p * 16 + cby) = (f16)h;
    }
    gv0 = gn0; gv1 = gn1; gv2 = gn2;
    BARLITE();

    // ---- P5: waves 0-3 export own half of h_{t+1}, release flag bit ----
    if (wave < 4) {
      u32x4 d = *reinterpret_cast<const u32x4*>(
          reinterpret_cast<const char*>(ha) + nxt + (hf4 + wave) * 1024 + lane * 16);
      *reinterpret_cast<u32x4*>(xchgWr + (size_t)((t + 1) & 1) * 4096 +
                                wave * 1024 + lane * 16) = d;
      asm volatile("s_waitcnt vmcnt(0)" ::: "memory");
      if (lane == 0)
        __hip_atomic_fetch_or(flagOwn + t + 1, 1u << wave, __ATOMIC_RELEASE,
                              __HIP_MEMORY_SCOPE_AGENT);
    }
  }

  // final: import partner half of h_512 (slot 0, parity 0), then last heads
  if (wave >= 4) {
    const unsigned msk = 1u << (wave - 4);
    while (!(__hip_atomic_load(flagPartner + 512, __ATOMIC_ACQUIRE,
                               __HIP_MEMORY_SCOPE_AGENT) & msk)) {}
    u32x4 d = *reinterpret_cast<const u32x4*>(xchgRd + (wave - 4) * 1024 + lane * 16);
    *reinterpret_cast<u32x4*>(reinterpret_cast<char*>(ha) +
                              (pf4 + (wave - 4)) * 1024 + lane * 16) = d;
  }
  BARLITE();
  if (wave < 4) head_tau(505 + hf4 + wave);  // hf0: 505..508, hf1: 509..512
}

extern "C" void kernel_launch(void* const* d_in, const int* in_sizes, int n_in,
                              void* d_out, int out_size, void* d_ws, size_t ws_size,
                              hipStream_t stream) {
  const float* x      = (const float*)d_in[0];
  const float* carry0 = (const float*)d_in[1];
  const float* Wi     = (const float*)d_in[2];
  const float* bi     = (const float*)d_in[3];
  const float* Wh     = (const float*)d_in[4];
  const float* bhn    = (const float*)d_in[5];
  const float* Wo     = (const float*)d_in[6];
  const float* bo     = (const float*)d_in[7];
  float* out = (float*)d_out;

  f16* gx  = (f16*)d_ws;                       // 512*256*768 f16 = 192 MiB
  f16* WiT = gx + (size_t)512 * 256 * 768;     // 768*256 f16 = 384 KiB
  // xchg (256 KB) + flags (~65 KB) alias the WiT region (dead after K1)
  char* xchg = (char*)WiT;                           // 32 * 8192 B
  unsigned int* flags = (unsigned int*)((char*)WiT + 262144);  // 16*2*520 u32

  k_prep_wit<<<dim3(768), dim3(256), 0, stream>>>(Wi, WiT);
  k_gemm_gx<<<dim3(6, 1024), dim3(256), 0, stream>>>(x, WiT, bi, gx);
  hipMemsetAsync(flags, 0, 16 * 2 * 520 * sizeof(unsigned int), stream);
  k_scan<<<dim3(32), dim3(512), 0, stream>>>(carry0, Wh, bhn, gx, Wo, bo, out,
                                             xchg, flags);
}

// Round 9
// 1081.936 us; speedup vs baseline: 2.6467x; 2.6467x over previous
//
#include <hip/hip_runtime.h>
#include <hip/hip_fp16.h>

typedef _Float16 f16;
typedef __attribute__((ext_vector_type(8))) _Float16 f16x8;
typedef __attribute__((ext_vector_type(4))) _Float16 f16x4;
typedef __attribute__((ext_vector_type(4))) float f32x4;
typedef __attribute__((ext_vector_type(4))) float float4v;
typedef long long i64;

// Shapes: x[512,256,256], carry0[256,256], Wi[256,768], bi[768],
//         Wh[256,768], bhn[256], Wo[256,16], bo[16] -> out[512,256,16] f32
//
// gx workspace layout (scan-fragment order, produced by K1), f16, SCALED x128:
//   vecidx = ((t*16 + blk)*8 + w8)*6 + (gate*2 + nt2)
//   element = vecidx*256 + lane*4 + j
//
// Scan scaling: h stored fp8 as 16*h; Wh fp8 as 8*Wh; Wo fp8 as 256*Wo;
// gx f16 as 128*gx. MFMA accs are 128*preact (exact pow2 folds).

static __device__ __forceinline__ float sigm_s(float x) {  // sigmoid(x/128)
  return __builtin_amdgcn_rcpf(1.0f + __expf(-0.0078125f * x));
}
static __device__ __forceinline__ float tanh_s(float x) {  // tanh(x/128)
  float e = __expf(0.015625f * x);
  return 1.0f - 2.0f * __builtin_amdgcn_rcpf(e + 1.0f);
}

// ---------------- K0: transpose+convert Wi -> WiT[768][256] f16 -------------
__global__ void k_prep_wit(const float* __restrict__ Wi, f16* __restrict__ WiT) {
  int n = blockIdx.x;
  int k = threadIdx.x;
  WiT[n * 256 + k] = (f16)Wi[(size_t)k * 768 + n];
}

// ---------------- K1: gx = 128*(x @ Wi + bi)  (fp16 MFMA, 128x128 tile) -----
__global__ __launch_bounds__(256, 4) void k_gemm_gx(
    const float* __restrict__ x, const f16* __restrict__ WiT,
    const float* __restrict__ bi, f16* __restrict__ gx) {
  __shared__ f16 As[128 * 64];
  __shared__ f16 Bs[128 * 64];
  const int tid = threadIdx.x;
  const int lane = tid & 63;
  const int wave = tid >> 6;
  const int wm = wave >> 1, wn = wave & 1;
  const int m0 = blockIdx.y * 128;
  const int n0 = blockIdx.x * 128;

  f32x4 acc[4][4] = {};

  for (int ks = 0; ks < 4; ++ks) {
    const int k0 = ks * 64;
#pragma unroll
    for (int i = 0; i < 8; ++i) {
      int c = i * 256 + tid;
      int row = c >> 4, cx = c & 15;
      float4v v = *reinterpret_cast<const float4v*>(
          x + (size_t)(m0 + row) * 256 + k0 + cx * 4);
      f16x4 hv;
      hv[0] = (f16)v[0]; hv[1] = (f16)v[1]; hv[2] = (f16)v[2]; hv[3] = (f16)v[3];
      int boff = row * 128 + ((cx * 8) ^ ((row & 7) << 4));
      *reinterpret_cast<f16x4*>(reinterpret_cast<char*>(As) + boff) = hv;
    }
#pragma unroll
    for (int i = 0; i < 4; ++i) {
      int c = i * 256 + tid;
      int n = c >> 3, cx = c & 7;
      f16x8 v = *reinterpret_cast<const f16x8*>(
          WiT + (size_t)(n0 + n) * 256 + k0 + cx * 8);
      int boff = n * 128 + ((cx * 16) ^ ((n & 7) << 4));
      *reinterpret_cast<f16x8*>(reinterpret_cast<char*>(Bs) + boff) = v;
    }
    __syncthreads();
#pragma unroll
    for (int kt = 0; kt < 2; ++kt) {
      const int kb = kt * 64 + ((lane >> 4) << 4);
      f16x8 a[4], b[4];
#pragma unroll
      for (int mt = 0; mt < 4; ++mt) {
        int r = wm * 64 + mt * 16 + (lane & 15);
        a[mt] = *reinterpret_cast<const f16x8*>(
            reinterpret_cast<const char*>(As) + r * 128 + (kb ^ ((r & 7) << 4)));
      }
#pragma unroll
      for (int nt = 0; nt < 4; ++nt) {
        int r = wn * 64 + nt * 16 + (lane & 15);
        b[nt] = *reinterpret_cast<const f16x8*>(
            reinterpret_cast<const char*>(Bs) + r * 128 + (kb ^ ((r & 7) << 4)));
      }
#pragma unroll
      for (int mt = 0; mt < 4; ++mt)
#pragma unroll
        for (int nt = 0; nt < 4; ++nt)
          acc[mt][nt] = __builtin_amdgcn_mfma_f32_16x16x32_f16(
              a[mt], b[nt], acc[mt][nt], 0, 0, 0);
    }
    __syncthreads();
  }
  const int t_  = blockIdx.y >> 1;
  const int bhf = blockIdx.y & 1;
  const int gg  = blockIdx.x >> 1;
  const int xh  = blockIdx.x & 1;
  float biv[4];
#pragma unroll
  for (int nt = 0; nt < 4; ++nt) biv[nt] = bi[n0 + wn * 64 + nt * 16 + (lane & 15)];
#pragma unroll
  for (int mt = 0; mt < 4; ++mt) {
    const int blk = bhf * 8 + wm * 4 + mt;
#pragma unroll
    for (int nt = 0; nt < 4; ++nt) {
      const int w = xh * 4 + wn * 2 + (nt >> 1);
      const int vecidx = ((t_ * 16 + blk) * 8 + w) * 6 + gg * 2 + (nt & 1);
      f16x4 hv;
#pragma unroll
      for (int r = 0; r < 4; ++r)
        hv[r] = (f16)((acc[mt][nt][r] + biv[nt]) * 128.0f);
      *reinterpret_cast<f16x4*>(gx + (size_t)vecidx * 256 + lane * 4) = hv;
    }
  }
}

// ---------------- K2: fp8 GRU scan + fused head, 16 blocks x 8 waves --------
// ALL Wh weights in fp8 register B-frags (96 VGPRs; x8 scale). h kept as fp8
// A-frags (x16 scale) in a 2-slot LDS ring: frame kt = 512B, granule
// g = khi*16+row at p = g^(g>>3) (read b64 lane-linear conflict-free; write
// 8 ds_write_b8/thread). Head fp8 (Wo x256) on wave 0 each step.
__global__ __launch_bounds__(512, 2) void k_scan(
    const float* __restrict__ carry0, const float* __restrict__ Wh,
    const float* __restrict__ bhn, const f16* __restrict__ gxL,
    const float* __restrict__ Wo, const float* __restrict__ bo,
    float* __restrict__ out) {
  __shared__ char ha[2 * 4096];  // 2 slots x 8 frames x 512B fp8 A-frags
  __shared__ char wofs[4096];    // 8 frames x 512B fp8 Wo B-frags
  const int tid = threadIdx.x;
  const int lane = tid & 63;
  const int wave = tid >> 6;  // 0..7
  const int l15 = lane & 15, l4 = lane >> 4;
  const int r0 = blockIdx.x * 16;

  // All 3 Wh gates -> fp8 register B-frags (i64 each = 2 VGPRs), scaled x8
  i64 whf[3][2][8];
#pragma unroll
  for (int g = 0; g < 3; ++g)
#pragma unroll
    for (int nt = 0; nt < 2; ++nt) {
      const int col = g * 256 + wave * 32 + nt * 16 + l15;
#pragma unroll
      for (int kt = 0; kt < 8; ++kt) {
        float w[8];
#pragma unroll
        for (int e = 0; e < 8; ++e)
          w[e] = Wh[(size_t)(kt * 32 + l4 * 8 + e) * 768 + col] * 8.0f;
        int lo = 0, hi = 0;
        lo = __builtin_amdgcn_cvt_pk_fp8_f32(w[0], w[1], lo, false);
        lo = __builtin_amdgcn_cvt_pk_fp8_f32(w[2], w[3], lo, true);
        hi = __builtin_amdgcn_cvt_pk_fp8_f32(w[4], w[5], hi, false);
        hi = __builtin_amdgcn_cvt_pk_fp8_f32(w[6], w[7], hi, true);
        whf[g][nt][kt] = (i64)(unsigned int)lo | ((i64)(unsigned int)hi << 32);
      }
    }
  // Wo -> fp8 LDS B-frags (x256); wave w builds frame kt=w
  {
    float w[8];
#pragma unroll
    for (int e = 0; e < 8; ++e)
      w[e] = Wo[(wave * 32 + l4 * 8 + e) * 16 + l15] * 256.0f;
    int lo = 0, hi = 0;
    lo = __builtin_amdgcn_cvt_pk_fp8_f32(w[0], w[1], lo, false);
    lo = __builtin_amdgcn_cvt_pk_fp8_f32(w[2], w[3], lo, true);
    hi = __builtin_amdgcn_cvt_pk_fp8_f32(w[4], w[5], hi, false);
    hi = __builtin_amdgcn_cvt_pk_fp8_f32(w[6], w[7], hi, true);
    *reinterpret_cast<int*>(wofs + wave * 512 + lane * 8) = lo;
    *reinterpret_cast<int*>(wofs + wave * 512 + lane * 8 + 4) = hi;
  }
  float bh128[2];
#pragma unroll
  for (int nt = 0; nt < 2; ++nt) bh128[nt] = 128.0f * bhn[wave * 32 + nt * 16 + l15];
  const float bov = bo[l15];

  // init h_0: hcur f32 + fp8 A-frags (x16) into slot 0 (wave owns frame=wave)
  float hcur[2][4];
#pragma unroll
  for (int nt = 0; nt < 2; ++nt) {
    const int gbase = (2 * nt + (l15 >> 3)) * 16 + l4 * 4;
    const int e8 = l15 & 7;
    float hs[4];
#pragma unroll
    for (int j = 0; j < 4; ++j) {
      float h = carry0[(size_t)(r0 + l4 * 4 + j) * 256 + wave * 32 + nt * 16 + l15];
      hcur[nt][j] = h;
      hs[j] = h * 16.0f;
    }
    int pk = 0;
    pk = __builtin_amdgcn_cvt_pk_fp8_f32(hs[0], hs[1], pk, false);
    pk = __builtin_amdgcn_cvt_pk_fp8_f32(hs[2], hs[3], pk, true);
#pragma unroll
    for (int j = 0; j < 4; ++j) {
      const int g = gbase + j;
      const int p = g ^ (g >> 3);
      ha[wave * 512 + p * 8 + e8] = (char)(pk >> (8 * j));
    }
  }
  __syncthreads();

  const f16* gp0 = gxL + ((size_t)blockIdx.x * 8 + wave) * 1536 + lane * 4;
  const int rdoff = (lane ^ (lane >> 3)) * 8;  // swizzled A-frag read offset

  f16x4 gva[6], gvb[6];
#pragma unroll
  for (int i = 0; i < 6; ++i)
    gva[i] = *reinterpret_cast<const f16x4*>(gp0 + i * 256);

  auto step = [&](int cur, int nxt, f16x4 (&gv)[6], f16x4 (&gvn)[6],
                  const f16* gpn, int tt) {
    // prefetch NEXT step's gx (in flight across light barrier)
#pragma unroll
    for (int i = 0; i < 6; ++i)
      gvn[i] = *reinterpret_cast<const f16x4*>(gpn + i * 256);

    // C-init (all x128): r,z from gx; n from 128*bhn
    f32x4 acc[3][2];
#pragma unroll
    for (int nt = 0; nt < 2; ++nt)
#pragma unroll
      for (int j = 0; j < 4; ++j) {
        acc[0][nt][j] = (float)gv[nt][j];
        acc[1][nt][j] = (float)gv[2 + nt][j];
        acc[2][nt][j] = bh128[nt];
      }
    // h A-frags (fp8, b64, conflict-free)
    i64 a[8];
#pragma unroll
    for (int kt = 0; kt < 8; ++kt)
      a[kt] = *reinterpret_cast<const i64*>(ha + cur + kt * 512 + rdoff);
#pragma unroll
    for (int kt = 0; kt < 8; ++kt)
#pragma unroll
      for (int nt = 0; nt < 2; ++nt) {
        acc[0][nt] = __builtin_amdgcn_mfma_f32_16x16x32_fp8_fp8(
            a[kt], whf[0][nt][kt], acc[0][nt], 0, 0, 0);
        acc[1][nt] = __builtin_amdgcn_mfma_f32_16x16x32_fp8_fp8(
            a[kt], whf[1][nt][kt], acc[1][nt], 0, 0, 0);
        acc[2][nt] = __builtin_amdgcn_mfma_f32_16x16x32_fp8_fp8(
            a[kt], whf[2][nt][kt], acc[2][nt], 0, 0, 0);
      }

    // fused head on wave 0: out[tt-1] = h_tt @ Wo (acc scale 16*256=4096)
    if (wave == 0) {
      f32x4 aco = {};
#pragma unroll
      for (int kt = 0; kt < 8; ++kt) {
        i64 ah = *reinterpret_cast<const i64*>(ha + cur + kt * 512 + rdoff);
        i64 wb = *reinterpret_cast<const i64*>(wofs + kt * 512 + lane * 8);
        aco = __builtin_amdgcn_mfma_f32_16x16x32_fp8_fp8(ah, wb, aco, 0, 0, 0);
      }
      if (tt > 0) {
#pragma unroll
        for (int r = 0; r < 4; ++r) {
          float y = fmaf(aco[r], 2.44140625e-4f, bov);  // /4096 + bo
          if (l15 >= 8) y = __expf(fminf(fmaxf(y, -20.0f), 2.0f));
          out[((size_t)(tt - 1) * 256 + r0 + l4 * 4 + r) * 16 + l15] = y;
        }
      }
    }

    // elementwise GRU + fp8 A-frag write of h_{t+1} into next slot
#pragma unroll
    for (int nt = 0; nt < 2; ++nt) {
      const int gbase = (2 * nt + (l15 >> 3)) * 16 + l4 * 4;
      const int e8 = l15 & 7;
      float hs[4];
#pragma unroll
      for (int j = 0; j < 4; ++j) {
        float rg = sigm_s(acc[0][nt][j]);
        float zg = sigm_s(acc[1][nt][j]);
        float ng = tanh_s((float)gv[4 + nt][j] + rg * acc[2][nt][j]);
        float h = ng + zg * (hcur[nt][j] - ng);
        hcur[nt][j] = h;
        hs[j] = h * 16.0f;
      }
      int pk = 0;
      pk = __builtin_amdgcn_cvt_pk_fp8_f32(hs[0], hs[1], pk, false);
      pk = __builtin_amdgcn_cvt_pk_fp8_f32(hs[2], hs[3], pk, true);
#pragma unroll
      for (int j = 0; j < 4; ++j) {
        const int g = gbase + j;
        const int p = g ^ (g >> 3);
        ha[nxt + wave * 512 + p * 8 + e8] = (char)(pk >> (8 * j));
      }
    }
    // lightweight barrier: order LDS h-handoff only (no vmcnt drain)
    asm volatile("s_waitcnt lgkmcnt(0)\n\ts_barrier" ::: "memory");
  };

  for (int t = 0; t < 512; t += 2) {
    const f16* gp1 = gp0 + (size_t)(t + 1) * 196608;
    const f16* gp2 = gp0 + (size_t)(t + 2 <= 511 ? t + 2 : 511) * 196608;
    step(0, 4096, gva, gvb, gp1, t);
    step(4096, 0, gvb, gva, gp2, t + 1);
  }

  // final head: out[511] = h_512 @ Wo (h_512 in slot 0)
  if (wave == 0) {
    f32x4 aco = {};
#pragma unroll
    for (int kt = 0; kt < 8; ++kt) {
      i64 ah = *reinterpret_cast<const i64*>(ha + kt * 512 + rdoff);
      i64 wb = *reinterpret_cast<const i64*>(wofs + kt * 512 + lane * 8);
      aco = __builtin_amdgcn_mfma_f32_16x16x32_fp8_fp8(ah, wb, aco, 0, 0, 0);
    }
#pragma unroll
    for (int r = 0; r < 4; ++r) {
      float y = fmaf(aco[r], 2.44140625e-4f, bov);
      if (l15 >= 8) y = __expf(fminf(fmaxf(y, -20.0f), 2.0f));
      out[((size_t)511 * 256 + r0 + l4 * 4 + r) * 16 + l15] = y;
    }
  }
}

extern "C" void kernel_launch(void* const* d_in, const int* in_sizes, int n_in,
                              void* d_out, int out_size, void* d_ws, size_t ws_size,
                              hipStream_t stream) {
  const float* x      = (const float*)d_in[0];
  const float* carry0 = (const float*)d_in[1];
  const float* Wi     = (const float*)d_in[2];
  const float* bi     = (const float*)d_in[3];
  const float* Wh     = (const float*)d_in[4];
  const float* bhn    = (const float*)d_in[5];
  const float* Wo     = (const float*)d_in[6];
  const float* bo     = (const float*)d_in[7];
  float* out = (float*)d_out;

  f16* gx  = (f16*)d_ws;                       // 512*256*768 f16 = 192 MiB
  f16* WiT = gx + (size_t)512 * 256 * 768;     // 768*256 f16

  k_prep_wit<<<dim3(768), dim3(256), 0, stream>>>(Wi, WiT);
  k_gemm_gx<<<dim3(6, 1024), dim3(256), 0, stream>>>(x, WiT, bi, gx);
  k_scan<<<dim3(16), dim3(512), 0, stream>>>(carry0, Wh, bhn, gx, Wo, bo, out);
}

// Round 10
// 1038.668 us; speedup vs baseline: 2.7570x; 1.0417x over previous
//
#include <hip/hip_runtime.h>
#include <hip/hip_fp16.h>

typedef _Float16 f16;
typedef __attribute__((ext_vector_type(8))) _Float16 f16x8;
typedef __attribute__((ext_vector_type(4))) _Float16 f16x4;
typedef __attribute__((ext_vector_type(4))) float f32x4;
typedef __attribute__((ext_vector_type(4))) float float4v;
typedef long long i64;

// Shapes: x[512,256,256], carry0[256,256], Wi[256,768], bi[768],
//         Wh[256,768], bhn[256], Wo[256,16], bo[16] -> out[512,256,16] f32
//
// gx workspace layout (scan-fragment order, produced by K1), f16, SCALED x128:
//   vecidx = ((t*16 + blk)*8 + w8)*6 + (gate*2 + nt2)
//   element = vecidx*256 + lane*4 + j
// K2 (16 waves of 16 cols): w8 = wave>>1, nt2 = wave&1.
//
// Scan scaling: h stored fp8 as 16*h; Wh fp8 as 8*Wh; Wo fp8 as 256*Wo;
// gx f16 as 128*gx. MFMA accs are 128*preact (exact pow2 folds).

static __device__ __forceinline__ float sigm_s(float x) {  // sigmoid(x/128)
  return __builtin_amdgcn_rcpf(1.0f + __expf(-0.0078125f * x));
}
static __device__ __forceinline__ float tanh_s(float x) {  // tanh(x/128)
  float e = __expf(0.015625f * x);
  return 1.0f - 2.0f * __builtin_amdgcn_rcpf(e + 1.0f);
}

// ---------------- K0: transpose+convert Wi -> WiT[768][256] f16 -------------
__global__ void k_prep_wit(const float* __restrict__ Wi, f16* __restrict__ WiT) {
  int n = blockIdx.x;
  int k = threadIdx.x;
  WiT[n * 256 + k] = (f16)Wi[(size_t)k * 768 + n];
}

// ---------------- K1: gx = 128*(x @ Wi + bi)  (fp16 MFMA, 128x128 tile) -----
__global__ __launch_bounds__(256, 4) void k_gemm_gx(
    const float* __restrict__ x, const f16* __restrict__ WiT,
    const float* __restrict__ bi, f16* __restrict__ gx) {
  __shared__ f16 As[128 * 64];
  __shared__ f16 Bs[128 * 64];
  const int tid = threadIdx.x;
  const int lane = tid & 63;
  const int wave = tid >> 6;
  const int wm = wave >> 1, wn = wave & 1;
  const int m0 = blockIdx.y * 128;
  const int n0 = blockIdx.x * 128;

  f32x4 acc[4][4] = {};

  for (int ks = 0; ks < 4; ++ks) {
    const int k0 = ks * 64;
#pragma unroll
    for (int i = 0; i < 8; ++i) {
      int c = i * 256 + tid;
      int row = c >> 4, cx = c & 15;
      float4v v = *reinterpret_cast<const float4v*>(
          x + (size_t)(m0 + row) * 256 + k0 + cx * 4);
      f16x4 hv;
      hv[0] = (f16)v[0]; hv[1] = (f16)v[1]; hv[2] = (f16)v[2]; hv[3] = (f16)v[3];
      int boff = row * 128 + ((cx * 8) ^ ((row & 7) << 4));
      *reinterpret_cast<f16x4*>(reinterpret_cast<char*>(As) + boff) = hv;
    }
#pragma unroll
    for (int i = 0; i < 4; ++i) {
      int c = i * 256 + tid;
      int n = c >> 3, cx = c & 7;
      f16x8 v = *reinterpret_cast<const f16x8*>(
          WiT + (size_t)(n0 + n) * 256 + k0 + cx * 8);
      int boff = n * 128 + ((cx * 16) ^ ((n & 7) << 4));
      *reinterpret_cast<f16x8*>(reinterpret_cast<char*>(Bs) + boff) = v;
    }
    __syncthreads();
#pragma unroll
    for (int kt = 0; kt < 2; ++kt) {
      const int kb = kt * 64 + ((lane >> 4) << 4);
      f16x8 a[4], b[4];
#pragma unroll
      for (int mt = 0; mt < 4; ++mt) {
        int r = wm * 64 + mt * 16 + (lane & 15);
        a[mt] = *reinterpret_cast<const f16x8*>(
            reinterpret_cast<const char*>(As) + r * 128 + (kb ^ ((r & 7) << 4)));
      }
#pragma unroll
      for (int nt = 0; nt < 4; ++nt) {
        int r = wn * 64 + nt * 16 + (lane & 15);
        b[nt] = *reinterpret_cast<const f16x8*>(
            reinterpret_cast<const char*>(Bs) + r * 128 + (kb ^ ((r & 7) << 4)));
      }
#pragma unroll
      for (int mt = 0; mt < 4; ++mt)
#pragma unroll
        for (int nt = 0; nt < 4; ++nt)
          acc[mt][nt] = __builtin_amdgcn_mfma_f32_16x16x32_f16(
              a[mt], b[nt], acc[mt][nt], 0, 0, 0);
    }
    __syncthreads();
  }
  const int t_  = blockIdx.y >> 1;
  const int bhf = blockIdx.y & 1;
  const int gg  = blockIdx.x >> 1;
  const int xh  = blockIdx.x & 1;
  float biv[4];
#pragma unroll
  for (int nt = 0; nt < 4; ++nt) biv[nt] = bi[n0 + wn * 64 + nt * 16 + (lane & 15)];
#pragma unroll
  for (int mt = 0; mt < 4; ++mt) {
    const int blk = bhf * 8 + wm * 4 + mt;
#pragma unroll
    for (int nt = 0; nt < 4; ++nt) {
      const int w = xh * 4 + wn * 2 + (nt >> 1);
      const int vecidx = ((t_ * 16 + blk) * 8 + w) * 6 + gg * 2 + (nt & 1);
      f16x4 hv;
#pragma unroll
      for (int r = 0; r < 4; ++r)
        hv[r] = (f16)((acc[mt][nt][r] + biv[nt]) * 128.0f);
      *reinterpret_cast<f16x4*>(gx + (size_t)vecidx * 256 + lane * 4) = hv;
    }
  }
}

// ---------------- K2: fp8 GRU scan, 16 blocks x 16 waves (4/SIMD) -----------
// Wave owns 16 H-cols; ALL its Wh weights in fp8 register B-frags (48 VGPRs,
// x8 scale). h kept as fp8 A-frags (x16) in a 2-slot LDS ring (read b64
// lane-linear conflict-free; write 4 byte-stores/thread). 4 waves/SIMD gives
// the phase-spread to overlap the MFMA and VALU pipes (R9 was 2/SIMD
// lockstep: both pipes ~50% serialized). Head fp8 on wave 0 each step.
__global__ __launch_bounds__(1024) void k_scan(
    const float* __restrict__ carry0, const float* __restrict__ Wh,
    const float* __restrict__ bhn, const f16* __restrict__ gxL,
    const float* __restrict__ Wo, const float* __restrict__ bo,
    float* __restrict__ out) {
  __shared__ char ha[2 * 4096];  // 2 slots x 8 frames x 512B fp8 A-frags
  __shared__ char wofs[4096];    // 8 frames x 512B fp8 Wo B-frags
  const int tid = threadIdx.x;
  const int lane = tid & 63;
  const int wave = tid >> 6;  // 0..15
  const int l15 = lane & 15, l4 = lane >> 4;
  const int r0 = blockIdx.x * 16;

  // 3 Wh gates for own 16 cols -> fp8 register B-frags (48 VGPRs), x8 scale
  i64 whf[3][8];
#pragma unroll
  for (int g = 0; g < 3; ++g) {
    const int col = g * 256 + wave * 16 + l15;
#pragma unroll
    for (int kt = 0; kt < 8; ++kt) {
      float w[8];
#pragma unroll
      for (int e = 0; e < 8; ++e)
        w[e] = Wh[(size_t)(kt * 32 + l4 * 8 + e) * 768 + col] * 8.0f;
      int lo = 0, hi = 0;
      lo = __builtin_amdgcn_cvt_pk_fp8_f32(w[0], w[1], lo, false);
      lo = __builtin_amdgcn_cvt_pk_fp8_f32(w[2], w[3], lo, true);
      hi = __builtin_amdgcn_cvt_pk_fp8_f32(w[4], w[5], hi, false);
      hi = __builtin_amdgcn_cvt_pk_fp8_f32(w[6], w[7], hi, true);
      whf[g][kt] = (i64)(unsigned int)lo | ((i64)(unsigned int)hi << 32);
    }
  }
  // Wo -> fp8 LDS B-frags (x256); waves 0-7 build frame kt=wave
  if (wave < 8) {
    float w[8];
#pragma unroll
    for (int e = 0; e < 8; ++e)
      w[e] = Wo[(wave * 32 + l4 * 8 + e) * 16 + l15] * 256.0f;
    int lo = 0, hi = 0;
    lo = __builtin_amdgcn_cvt_pk_fp8_f32(w[0], w[1], lo, false);
    lo = __builtin_amdgcn_cvt_pk_fp8_f32(w[2], w[3], lo, true);
    hi = __builtin_amdgcn_cvt_pk_fp8_f32(w[4], w[5], hi, false);
    hi = __builtin_amdgcn_cvt_pk_fp8_f32(w[6], w[7], hi, true);
    *reinterpret_cast<int*>(wofs + wave * 512 + lane * 8) = lo;
    *reinterpret_cast<int*>(wofs + wave * 512 + lane * 8 + 4) = hi;
  }
  const float bh128 = 128.0f * bhn[wave * 16 + l15];
  const float bov = bo[l15];

  // init h_0: hcur f32 + fp8 A-frags (x16) into slot 0
  // col c = wave*16+l15: frame f = wave>>1, s = (wave&1)*2 + (l15>>3),
  // granule g = s*16+row at p = g^(g>>3), byte e8 = l15&7
  const int fme = wave >> 1;
  const int sme = (wave & 1) * 2 + (l15 >> 3);
  const int e8 = l15 & 7;
  float hcur[4];
  {
    float hs[4];
#pragma unroll
    for (int j = 0; j < 4; ++j) {
      float h = carry0[(size_t)(r0 + l4 * 4 + j) * 256 + wave * 16 + l15];
      hcur[j] = h;
      hs[j] = h * 16.0f;
    }
    int pk = 0;
    pk = __builtin_amdgcn_cvt_pk_fp8_f32(hs[0], hs[1], pk, false);
    pk = __builtin_amdgcn_cvt_pk_fp8_f32(hs[2], hs[3], pk, true);
#pragma unroll
    for (int j = 0; j < 4; ++j) {
      const int g = sme * 16 + l4 * 4 + j;
      const int p = g ^ (g >> 3);
      ha[fme * 512 + p * 8 + e8] = (char)(pk >> (8 * j));
    }
  }
  __syncthreads();

  // gx: gate g at gpt + g*512 (f16 elems); per-t stride 196608
  const f16* gp0 = gxL + (((size_t)blockIdx.x * 8 + (wave >> 1)) * 6 +
                          (size_t)(wave & 1)) * 256 + (size_t)lane * 4;
  const int rdoff = (lane ^ (lane >> 3)) * 8;  // swizzled A-frag read offset

  f16x4 gva[3], gvb[3];
#pragma unroll
  for (int g = 0; g < 3; ++g)
    gva[g] = *reinterpret_cast<const f16x4*>(gp0 + g * 512);

  auto step = [&](int cur, int nxt, f16x4 (&gv)[3], f16x4 (&gvn)[3],
                  const f16* gpn, int tt) {
    // prefetch NEXT step's gx (in flight across light barrier)
#pragma unroll
    for (int g = 0; g < 3; ++g)
      gvn[g] = *reinterpret_cast<const f16x4*>(gpn + g * 512);

    // C-init (all x128): r,z from gx; n from 128*bhn
    f32x4 acc0, acc1, acc2;
#pragma unroll
    for (int j = 0; j < 4; ++j) {
      acc0[j] = (float)gv[0][j];
      acc1[j] = (float)gv[1][j];
      acc2[j] = bh128;
    }
    // h A-frags (fp8, b64, conflict-free) + MFMA chains
#pragma unroll
    for (int kt = 0; kt < 8; ++kt) {
      i64 a = *reinterpret_cast<const i64*>(ha + cur + kt * 512 + rdoff);
      acc0 = __builtin_amdgcn_mfma_f32_16x16x32_fp8_fp8(a, whf[0][kt], acc0, 0, 0, 0);
      acc1 = __builtin_amdgcn_mfma_f32_16x16x32_fp8_fp8(a, whf[1][kt], acc1, 0, 0, 0);
      acc2 = __builtin_amdgcn_mfma_f32_16x16x32_fp8_fp8(a, whf[2][kt], acc2, 0, 0, 0);
    }

    // fused head on wave 0: out[tt-1] = h_tt @ Wo (acc scale 16*256=4096)
    if (wave == 0) {
      f32x4 aco = {};
#pragma unroll
      for (int kt = 0; kt < 8; ++kt) {
        i64 ah = *reinterpret_cast<const i64*>(ha + cur + kt * 512 + rdoff);
        i64 wb = *reinterpret_cast<const i64*>(wofs + kt * 512 + lane * 8);
        aco = __builtin_amdgcn_mfma_f32_16x16x32_fp8_fp8(ah, wb, aco, 0, 0, 0);
      }
      if (tt > 0) {
#pragma unroll
        for (int r = 0; r < 4; ++r) {
          float y = fmaf(aco[r], 2.44140625e-4f, bov);  // /4096 + bo
          if (l15 >= 8) y = __expf(fminf(fmaxf(y, -20.0f), 2.0f));
          out[((size_t)(tt - 1) * 256 + r0 + l4 * 4 + r) * 16 + l15] = y;
        }
      }
    }

    // elementwise GRU + fp8 A-frag write of h_{t+1} into next slot
    {
      float hs[4];
#pragma unroll
      for (int j = 0; j < 4; ++j) {
        float rg = sigm_s(acc0[j]);
        float zg = sigm_s(acc1[j]);
        float ng = tanh_s((float)gv[2][j] + rg * acc2[j]);
        float h = ng + zg * (hcur[j] - ng);
        hcur[j] = h;
        hs[j] = h * 16.0f;
      }
      int pk = 0;
      pk = __builtin_amdgcn_cvt_pk_fp8_f32(hs[0], hs[1], pk, false);
      pk = __builtin_amdgcn_cvt_pk_fp8_f32(hs[2], hs[3], pk, true);
#pragma unroll
      for (int j = 0; j < 4; ++j) {
        const int g = sme * 16 + l4 * 4 + j;
        const int p = g ^ (g >> 3);
        ha[nxt + fme * 512 + p * 8 + e8] = (char)(pk >> (8 * j));
      }
    }
    // lightweight barrier: order LDS h-handoff only (no vmcnt drain)
    asm volatile("s_waitcnt lgkmcnt(0)\n\ts_barrier" ::: "memory");
  };

  for (int t = 0; t < 512; t += 2) {
    const f16* gp1 = gp0 + (size_t)(t + 1) * 196608;
    const f16* gp2 = gp0 + (size_t)(t + 2 <= 511 ? t + 2 : 511) * 196608;
    step(0, 4096, gva, gvb, gp1, t);
    step(4096, 0, gvb, gva, gp2, t + 1);
  }

  // final head: out[511] = h_512 @ Wo (h_512 in slot 0)
  if (wave == 0) {
    f32x4 aco = {};
#pragma unroll
    for (int kt = 0; kt < 8; ++kt) {
      i64 ah = *reinterpret_cast<const i64*>(ha + kt * 512 + rdoff);
      i64 wb = *reinterpret_cast<const i64*>(wofs + kt * 512 + lane * 8);
      aco = __builtin_amdgcn_mfma_f32_16x16x32_fp8_fp8(ah, wb, aco, 0, 0, 0);
    }
#pragma unroll
    for (int r = 0; r < 4; ++r) {
      float y = fmaf(aco[r], 2.44140625e-4f, bov);
      if (l15 >= 8) y = __expf(fminf(fmaxf(y, -20.0f), 2.0f));
      out[((size_t)511 * 256 + r0 + l4 * 4 + r) * 16 + l15] = y;
    }
  }
}

extern "C" void kernel_launch(void* const* d_in, const int* in_sizes, int n_in,
                              void* d_out, int out_size, void* d_ws, size_t ws_size,
                              hipStream_t stream) {
  const float* x      = (const float*)d_in[0];
  const float* carry0 = (const float*)d_in[1];
  const float* Wi     = (const float*)d_in[2];
  const float* bi     = (const float*)d_in[3];
  const float* Wh     = (const float*)d_in[4];
  const float* bhn    = (const float*)d_in[5];
  const float* Wo     = (const float*)d_in[6];
  const float* bo     = (const float*)d_in[7];
  float* out = (float*)d_out;

  f16* gx  = (f16*)d_ws;                       // 512*256*768 f16 = 192 MiB
  f16* WiT = gx + (size_t)512 * 256 * 768;     // 768*256 f16

  k_prep_wit<<<dim3(768), dim3(256), 0, stream>>>(Wi, WiT);
  k_gemm_gx<<<dim3(6, 1024), dim3(256), 0, stream>>>(x, WiT, bi, gx);
  k_scan<<<dim3(16), dim3(1024), 0, stream>>>(carry0, Wh, bhn, gx, Wo, bo, out);
}